// Round 2
// baseline (1646.661 us; speedup 1.0000x reference)
//
#include <hip/hip_runtime.h>

#define B_ 64
#define L_ 2048
#define G_ 512
#define F_ 3072
#define N_ 5632
#define NT_ 360448
#define EG_ 16384
#define E_ 1048576
#define EPS_ 1e-5f
#define CSTF_ 68     // f32 cat tile stride (272B rows, 16B-aligned; ~2-4 way banks on ds_add)
#define KTOT_ 3584   // md GEMM K = G + F
#define KCH_ 896     // md GEMM K-chunk (4 chunks)
#define TCAP_ 384    // per-tile edge capacity (realized max span ~255)

typedef __attribute__((ext_vector_type(8))) short bf8v;
typedef __attribute__((ext_vector_type(4))) float f4v;

__device__ __forceinline__ unsigned short f2bf(float f){
  unsigned int u=__float_as_uint(f);
  unsigned int r=(u + 0x7fffu + ((u>>16)&1u))>>16;
  return (unsigned short)r;
}
__device__ __forceinline__ float bf2f(unsigned short h){
  return __uint_as_float(((unsigned int)h)<<16);
}

// ---------------- single prep dispatch ----------------
// blocks 0..87      : per-tile CSR build (LDS hist -> scan -> scatter), packed (src|dst<<16)
// blocks 88..599    : wcat build + outmd demand init
// blocks 600..11863 : encoder + fused LN (produces hnA)
__global__ __launch_bounds__(256) void k_prep(const int* __restrict__ ei,
    unsigned short* __restrict__ wcat,
    const float* __restrict__ wrel, const float* __restrict__ wroot,
    int* __restrict__ offT, int* __restrict__ srcs2,
    const float* __restrict__ x, const int* __restrict__ loci, float* __restrict__ outmd,
    unsigned short* __restrict__ hn, const float* __restrict__ ew, const float* __restrict__ eb,
    const float* __restrict__ lng, const float* __restrict__ lnb){
  int bid=blockIdx.x, tid=threadIdx.x;
  if(bid>=600){
    // ---- encoder + LN ----
    int lane=tid&63, wid=tid>>6;
    int node0=(bid-600)*32+wid*8;
    float w[7];
    #pragma unroll
    for(int k=0;k<7;k++) w[k]=ew[lane*7+k];
    float bias=eb[lane], gam=lng[lane], bet=lnb[lane];
    for(int t=0;t<8;t++){
      long n=node0+t;
      float acc=bias;
      #pragma unroll
      for(int k=0;k<7;k++) acc += x[n*7+k]*w[k];
      acc=fmaxf(acc,0.f);
      float s1=acc, s2=acc*acc;
      #pragma unroll
      for(int o=32;o>0;o>>=1){ s1+=__shfl_xor(s1,o,64); s2+=__shfl_xor(s2,o,64); }
      float mu=s1*(1.f/64.f);
      float var=s2*(1.f/64.f)-mu*mu;
      float inv=rsqrtf(var+EPS_);
      hn[n*64+lane]=f2bf((acc-mu)*inv*gam+bet);
    }
    return;
  }
  if(bid>=88){
    int i=(bid-88)*256+tid;          // 512 blocks -> 131072 = B_*L_
    if(i<B_*L_) outmd[i]=x[(long)loci[i]*7];
    if(i<32768){
      int l=i>>13; int rest=i&8191; int n=rest>>7; int k=rest&127;
      float v=(k<64)? wrel[((long)l*64+n)*64+k] : wroot[((long)l*64+n)*64+(k-64)];
      wcat[i]=f2bf(v);
    }
    return;
  }
  __shared__ int cnt64[64], cur64[64];
  int nb=bid*64;
  if(tid<64) cnt64[tid]=0;
  __syncthreads();
  for(int e=tid;e<EG_;e+=256){
    int d=ei[E_+e];
    unsigned t=(unsigned)(d-nb);
    if(t<64u) atomicAdd(&cnt64[t],1);
  }
  __syncthreads();
  if(tid<64){
    int v=cnt64[tid], s=v;
    #pragma unroll
    for(int o=1;o<64;o<<=1){ int u=__shfl_up(s,o,64); if(tid>=o) s+=u; }
    int ex=s-v;
    offT[bid*65+tid]=ex;
    cur64[tid]=ex;
    if(tid==63) offT[bid*65+64]=s;
  }
  __syncthreads();
  for(int e=tid;e<EG_;e+=256){
    int s=ei[e];
    int d=ei[E_+e];
    unsigned t=(unsigned)(d-nb);
    if(t<64u){
      int p=atomicAdd(&cur64[t],1);
      if(p<TCAP_) srcs2[bid*TCAP_+p]=s|(d<<16);
    }
  }
}

__device__ __forceinline__ void accrow(float* catf, int nodebase, int lig, int u,
                                       uint4 qa, uint4 qb){
  float* cb=&catf[((u>>16)-nodebase)*CSTF_ + (lig<<4)];
  unsigned int t[8]={qa.x,qa.y,qa.z,qa.w,qb.x,qb.y,qb.z,qb.w};
  #pragma unroll
  for(int j=0;j<8;j++){
    atomicAdd(cb+2*j,   __uint_as_float(t[j]<<16));
    atomicAdd(cb+2*j+1, __uint_as_float(t[j]&0xffff0000u));
  }
}

// ---------------- fused layer: balanced LDS-atomic gather -> MFMA -> epilogue (barrier-free) ----------------
// wave w owns dst rows [w*16,w*16+16). Gather: wave's edge range split into 16 equal
// contiguous chunks (one per 4-lane group); each lane covers 16 channels; accumulation
// via ds_add_f32 into an f32 LDS tile. One dependency round of loads per ~4 edges/group.
__global__ __launch_bounds__(256,8) void k_layer(const unsigned short* __restrict__ hs,
    unsigned short* __restrict__ hd, const int* __restrict__ offT, const int* __restrict__ srcs2,
    const unsigned short* __restrict__ wcat, const float* __restrict__ brel,
    const float* __restrict__ lng, const float* __restrict__ lnb, int do_ln){
  __shared__ float catf[64*CSTF_];
  int tid=threadIdx.x;
  int w=tid>>6, lane=tid&63;
  int bid=blockIdx.x;
  const int P=N_/64;                 // 88 tiles per graph
  int r8=bid/(8*P), rem=bid%(8*P);
  int xcd=rem&7, jj=rem>>3, g=r8*8+xcd;   // one graph per XCD's L2
  int nodebase=jj*64;
  const unsigned short* hg = hs + (size_t)g*N_*64;
  int w16=w*16;

  // ---- phase 1: balanced gather into f32 LDS tile via ds_add_f32 ----
  {
    int rl=lane>>2;                  // local row 0..15 (zeroing) / group id (gather)
    int lig=lane&3;                  // lane-in-group: channels [lig*16, lig*16+16)
    float* zb=&catf[(w16+rl)*CSTF_ + (lig<<4)];
    float4 z4={0.f,0.f,0.f,0.f};
    *(float4*)(zb)=z4; *(float4*)(zb+4)=z4; *(float4*)(zb+8)=z4; *(float4*)(zb+12)=z4;

    int kb=__builtin_amdgcn_readfirstlane(offT[jj*65+w16]);
    int ke=__builtin_amdgcn_readfirstlane(offT[jj*65+w16+16]);
    int cnt=ke-kb;
    int chunk=(cnt+15)>>4;
    int g0=kb+rl*chunk;
    int g1=g0+chunk; if(g1>ke) g1=ke;
    const int* esp=srcs2 + jj*TCAP_;
    for(int p=g0;p<g1;p+=4){
      int nrem=g1-p;
      int u0=esp[p];
      int u1=esp[(nrem>1)?p+1:p];
      int u2=esp[(nrem>2)?p+2:p];
      int u3=esp[(nrem>3)?p+3:p];
      const unsigned short* r0=hg+(size_t)(u0&0xffff)*64+(lig<<4);
      const unsigned short* r1=hg+(size_t)(u1&0xffff)*64+(lig<<4);
      const unsigned short* r2=hg+(size_t)(u2&0xffff)*64+(lig<<4);
      const unsigned short* r3=hg+(size_t)(u3&0xffff)*64+(lig<<4);
      uint4 a0=*(const uint4*)r0, b0=*(const uint4*)(r0+8);
      uint4 a1=*(const uint4*)r1, b1=*(const uint4*)(r1+8);
      uint4 a2=*(const uint4*)r2, b2=*(const uint4*)(r2+8);
      uint4 a3=*(const uint4*)r3, b3=*(const uint4*)(r3+8);
      accrow(catf,nodebase,lig,u0,a0,b0);
      if(nrem>1) accrow(catf,nodebase,lig,u1,a1,b1);
      if(nrem>2) accrow(catf,nodebase,lig,u2,a2,b2);
      if(nrem>3) accrow(catf,nodebase,lig,u3,a3,b3);
    }
  }
  // no barrier: wave w writes and reads only cat rows [w16, w16+16)

  // ---- phase 2: MFMA [agg|root] @ Wcat^T, fused epilogue ----
  int m=lane&15, quad=lane>>4;
  int row=w16+m;
  const float* arow=&catf[row*CSTF_];
  float4 c0=*(const float4*)(arow+quad*8);
  float4 c1=*(const float4*)(arow+quad*8+4);
  float4 c2=*(const float4*)(arow+32+quad*8);
  float4 c3=*(const float4*)(arow+32+quad*8+4);
  bf8v af0, af1;
  af0[0]=(short)f2bf(c0.x); af0[1]=(short)f2bf(c0.y);
  af0[2]=(short)f2bf(c0.z); af0[3]=(short)f2bf(c0.w);
  af0[4]=(short)f2bf(c1.x); af0[5]=(short)f2bf(c1.y);
  af0[6]=(short)f2bf(c1.z); af0[7]=(short)f2bf(c1.w);
  af1[0]=(short)f2bf(c2.x); af1[1]=(short)f2bf(c2.y);
  af1[2]=(short)f2bf(c2.z); af1[3]=(short)f2bf(c2.w);
  af1[4]=(short)f2bf(c3.x); af1[5]=(short)f2bf(c3.y);
  af1[6]=(short)f2bf(c3.z); af1[7]=(short)f2bf(c3.w);
  const unsigned short* hrow=hg+(size_t)(nodebase+row)*64;
  bf8v af2=*(const bf8v*)(hrow+quad*8);
  bf8v af3=*(const bf8v*)(hrow+32+quad*8);
  f4v acc[4];
  float bias_nt[4], g_nt[4], b_nt[4];
  #pragma unroll
  for(int nt=0;nt<4;nt++){
    int c=nt*16+m;
    bias_nt[nt]=brel[c];
    g_nt[nt]=lng[c]; b_nt[nt]=lnb[c];
    acc[nt]=(f4v){0.f,0.f,0.f,0.f};
    const unsigned short* wrow=wcat + (long)c*128 + quad*8;
    bf8v b0=*(const bf8v*)(wrow);
    bf8v b1=*(const bf8v*)(wrow+32);
    bf8v b2=*(const bf8v*)(wrow+64);
    bf8v b3=*(const bf8v*)(wrow+96);
    acc[nt]=__builtin_amdgcn_mfma_f32_16x16x32_bf16(af0,b0,acc[nt],0,0,0);
    acc[nt]=__builtin_amdgcn_mfma_f32_16x16x32_bf16(af1,b1,acc[nt],0,0,0);
    acc[nt]=__builtin_amdgcn_mfma_f32_16x16x32_bf16(af2,b2,acc[nt],0,0,0);
    acc[nt]=__builtin_amdgcn_mfma_f32_16x16x32_bf16(af3,b3,acc[nt],0,0,0);
  }
  float v[4][4];
  #pragma unroll
  for(int nt=0;nt<4;nt++)
    #pragma unroll
    for(int r=0;r<4;r++)
      v[nt][r]=fmaxf(acc[nt][r]+bias_nt[nt],0.f);
  if(do_ln){
    #pragma unroll
    for(int r=0;r<4;r++){
      float rs=v[0][r]+v[1][r]+v[2][r]+v[3][r];
      float rss=v[0][r]*v[0][r]+v[1][r]*v[1][r]+v[2][r]*v[2][r]+v[3][r]*v[3][r];
      #pragma unroll
      for(int o=1;o<16;o<<=1){ rs+=__shfl_xor(rs,o,64); rss+=__shfl_xor(rss,o,64); }
      float mu=rs*(1.f/64.f);
      float var=rss*(1.f/64.f)-mu*mu;
      float inv=rsqrtf(var+EPS_);
      #pragma unroll
      for(int nt=0;nt<4;nt++) v[nt][r]=(v[nt][r]-mu)*inv*g_nt[nt]+b_nt[nt];
    }
  }
  size_t rowbase=(size_t)g*N_ + nodebase + w16 + quad*4;
  #pragma unroll
  for(int r=0;r<4;r++){
    unsigned short* out=hd + (rowbase+r)*64;
    #pragma unroll
    for(int nt=0;nt<4;nt++) out[nt*16+m]=f2bf(v[nt][r]);
  }
}

// ---------------- merged readouts; also emit double-bf16 pf rows for md GEMM ----------------
__global__ __launch_bounds__(256) void k_readout2(const unsigned short* __restrict__ h,
    const int* __restrict__ prodi, const int* __restrict__ linei,
    const float* __restrict__ pw, const float* __restrict__ pb,
    const float* __restrict__ fw, const float* __restrict__ fb,
    float* __restrict__ outp, float* __restrict__ outf,
    unsigned short* __restrict__ pfhi, unsigned short* __restrict__ pflo){
  int i=blockIdx.x*256+threadIdx.x;
  const int MP=B_*G_;
  const int MT=MP+B_*F_;
  if(i>=MT) return;
  bool isp=i<MP;
  int j=isp? i : i-MP;
  long n=isp? (long)prodi[j] : (long)linei[j];
  const float* wv=isp? pw:fw;
  float acc=isp? pb[0]:fb[0];
  const uint4* hp=(const uint4*)(h+n*64);
  #pragma unroll
  for(int c=0;c<8;c++){
    uint4 u=hp[c];
    unsigned int uu[4]={u.x,u.y,u.z,u.w};
    #pragma unroll
    for(int q=0;q<4;q++){
      float lo=__uint_as_float(uu[q]<<16);
      float hi=__uint_as_float(uu[q]&0xffff0000u);
      acc += lo*wv[c*8+2*q] + hi*wv[c*8+2*q+1];
    }
  }
  int b,kcol;
  if(isp){ outp[j]=acc; b=j/G_; kcol=j%G_; }
  else   { outf[j]=acc; b=j/F_; kcol=G_+j%F_; }
  unsigned short hi=f2bf(acc);
  pfhi[(long)b*KTOT_+kcol]=hi;
  pflo[(long)b*KTOT_+kcol]=f2bf(acc-bf2f(hi));
}

// ---------------- md dense GEMM: outmd[b][l] -= sum_k mask[l][k]*pf[b][k] ----------------
// outmd pre-initialized with demand by k_prep; atomics accumulate -acc directly.
__global__ __launch_bounds__(256) void k_md_gemm(const float* __restrict__ gm, const float* __restrict__ lm,
    const unsigned short* __restrict__ pfhi, const unsigned short* __restrict__ pflo,
    float* __restrict__ outmd){
  int tid=threadIdx.x;
  int w=tid>>6, lane=tid&63;
  int m=lane&15, quad=lane>>4;
  int lb=blockIdx.x>>2, kc=blockIdx.x&3;
  int l=lb*64 + w*16 + m;              // A (mask) row for this lane
  f4v acc[4];
  #pragma unroll
  for(int nt=0;nt<4;nt++) acc[nt]=(f4v){0.f,0.f,0.f,0.f};
  int kk0=kc*KCH_;
  for(int s=0;s<KCH_/32;s++){
    int kk=kk0+s*32;
    const float* ap = (kk<G_)? gm + (long)l*G_ + kk : lm + (long)l*F_ + (kk-G_);
    float4 a0=*(const float4*)(ap+quad*8);
    float4 a1=*(const float4*)(ap+quad*8+4);
    bf8v af;
    af[0]=(short)f2bf(a0.x); af[1]=(short)f2bf(a0.y);
    af[2]=(short)f2bf(a0.z); af[3]=(short)f2bf(a0.w);
    af[4]=(short)f2bf(a1.x); af[5]=(short)f2bf(a1.y);
    af[6]=(short)f2bf(a1.z); af[7]=(short)f2bf(a1.w);
    #pragma unroll
    for(int nt=0;nt<4;nt++){
      int b=nt*16+m;
      const unsigned short* bp=pfhi + (long)b*KTOT_ + kk + quad*8;
      const unsigned short* lp=pflo + (long)b*KTOT_ + kk + quad*8;
      bf8v bh=*(const bf8v*)bp;
      bf8v bl=*(const bf8v*)lp;
      acc[nt]=__builtin_amdgcn_mfma_f32_16x16x32_bf16(af,bh,acc[nt],0,0,0);
      acc[nt]=__builtin_amdgcn_mfma_f32_16x16x32_bf16(af,bl,acc[nt],0,0,0);
    }
  }
  int lrow=lb*64 + w*16 + quad*4;
  #pragma unroll
  for(int r=0;r<4;r++)
    #pragma unroll
    for(int nt=0;nt<4;nt++)
      atomicAdd(&outmd[(long)(nt*16+m)*L_ + lrow+r], -acc[nt][r]);
}

extern "C" void kernel_launch(void* const* d_in, const int* in_sizes, int n_in,
                              void* d_out, int out_size, void* d_ws, size_t ws_size,
                              hipStream_t stream){
  const float* x    =(const float*)d_in[0];
  const int*   ei   =(const int*)d_in[1];
  const int*   prodi=(const int*)d_in[2];
  const int*   linei=(const int*)d_in[3];
  const int*   loci =(const int*)d_in[4];
  const float* ew   =(const float*)d_in[5];
  const float* eb   =(const float*)d_in[6];
  const float* lng  =(const float*)d_in[7];
  const float* lnb  =(const float*)d_in[8];
  const float* wrel =(const float*)d_in[9];
  const float* brel =(const float*)d_in[10];
  const float* wroot=(const float*)d_in[11];
  const float* pw   =(const float*)d_in[12];
  const float* pb   =(const float*)d_in[13];
  const float* fw   =(const float*)d_in[14];
  const float* fb   =(const float*)d_in[15];
  const float* gm   =(const float*)d_in[16];
  const float* lm   =(const float*)d_in[17];

  char* ws=(char*)d_ws;
  unsigned short* hnA =(unsigned short*)ws;                        // NT*64 bf16
  unsigned short* hnB =hnA + (size_t)NT_*64;                       // NT*64 bf16
  unsigned short* wcat=hnB + (size_t)NT_*64;                       // 32768 bf16
  unsigned short* pfhi=wcat + 32768;                               // B*KTOT bf16
  unsigned short* pflo=pfhi + (size_t)B_*KTOT_;                    // B*KTOT bf16
  int* offT =(int*)(pflo + (size_t)B_*KTOT_);                      // 88*65 int
  int* srcs2=offT + 88*65;                                         // 88*TCAP int

  float* outp =(float*)d_out;
  float* outf =outp + (size_t)B_*G_;
  float* outmd=outf + (size_t)B_*F_;

  k_prep<<<600+NT_/32,256,0,stream>>>(ei,wcat,wrel,wroot,offT,srcs2,
                                      x,loci,outmd,hnA,ew,eb,lng,lnb);
  for(int i=0;i<4;i++){
    const unsigned short* hs=(i&1)?hnB:hnA;
    unsigned short* hd=(i&1)?hnA:hnB;
    k_layer<<<B_*(N_/64),256,0,stream>>>(hs,hd,offT,srcs2,wcat+(size_t)i*8192,
        brel+(size_t)i*64,lng,lnb,(i<3)?1:0);
  }
  // after 4 layers (A->B->A->B->A) result is in hnA
  {
    int MT=B_*(G_+F_);
    k_readout2<<<(MT+255)/256,256,0,stream>>>(hnA,prodi,linei,pw,pb,fw,fb,outp,outf,pfhi,pflo);
  }
  k_md_gemm<<<128,256,0,stream>>>(gm,lm,pfhi,pflo,outmd);
}

// Round 3
// 404.030 us; speedup vs baseline: 4.0756x; 4.0756x over previous
//
#include <hip/hip_runtime.h>

#define B_ 64
#define L_ 2048
#define G_ 512
#define F_ 3072
#define N_ 5632
#define NT_ 360448
#define EG_ 16384
#define E_ 1048576
#define EPS_ 1e-5f
#define KTOT_ 3584   // md GEMM K = G + F
#define KCH_ 448     // md GEMM K-chunk (8 chunks)
#define TCAP_ 384    // per-tile edge capacity (realized max span ~255)

typedef __attribute__((ext_vector_type(8))) short bf8v;
typedef __attribute__((ext_vector_type(4))) float f4v;

__device__ __forceinline__ unsigned short f2bf(float f){
  unsigned int u=__float_as_uint(f);
  unsigned int r=(u + 0x7fffu + ((u>>16)&1u))>>16;
  return (unsigned short)r;
}
__device__ __forceinline__ float bf2f(unsigned short h){
  return __uint_as_float(((unsigned int)h)<<16);
}

// ---------------- single prep dispatch ----------------
// blocks 0..87      : per-tile CSR build over SHARED topology (graph-0 edges)
// blocks 88..599    : wcat build + outmd demand init
// blocks 600..11863 : encoder + fused LN -> hnA in [node][g*64+c] layout
__global__ __launch_bounds__(256) void k_prep(const int* __restrict__ ei,
    unsigned short* __restrict__ wcat,
    const float* __restrict__ wrel, const float* __restrict__ wroot,
    int* __restrict__ offT, int* __restrict__ srcs2,
    const float* __restrict__ x, const int* __restrict__ loci, float* __restrict__ outmd,
    unsigned short* __restrict__ hn, const float* __restrict__ ew, const float* __restrict__ eb,
    const float* __restrict__ lng, const float* __restrict__ lnb){
  int bid=blockIdx.x, tid=threadIdx.x;
  if(bid>=600){
    // ---- encoder + LN ----
    int lane=tid&63, wid=tid>>6;
    int idx=bid-600;                 // 0..11263
    int gid=idx/176;                 // graph 0..63
    int nch=idx%176;                 // node chunk (32 nodes each)
    int n0=nch*32+wid*8;
    float w[7];
    #pragma unroll
    for(int k=0;k<7;k++) w[k]=ew[lane*7+k];
    float bias=eb[lane], gam=lng[lane], bet=lnb[lane];
    for(int t=0;t<8;t++){
      int n=n0+t;
      long xrow=(long)gid*N_+n;
      float acc=bias;
      #pragma unroll
      for(int k=0;k<7;k++) acc += x[xrow*7+k]*w[k];
      acc=fmaxf(acc,0.f);
      float s1=acc, s2=acc*acc;
      #pragma unroll
      for(int o=32;o>0;o>>=1){ s1+=__shfl_xor(s1,o,64); s2+=__shfl_xor(s2,o,64); }
      float mu=s1*(1.f/64.f);
      float var=s2*(1.f/64.f)-mu*mu;
      float inv=rsqrtf(var+EPS_);
      hn[(size_t)n*4096 + gid*64 + lane]=f2bf((acc-mu)*inv*gam+bet);
    }
    return;
  }
  if(bid>=88){
    int i=(bid-88)*256+tid;          // 512 blocks -> 131072 = B_*L_
    if(i<B_*L_) outmd[i]=x[(long)loci[i]*7];
    if(i<32768){
      int l=i>>13; int rest=i&8191; int n=rest>>7; int k=rest&127;
      float v=(k<64)? wrel[((long)l*64+n)*64+k] : wroot[((long)l*64+n)*64+(k-64)];
      wcat[i]=f2bf(v);
    }
    return;
  }
  __shared__ int cnt64[64], cur64[64];
  int nb=bid*64;
  if(tid<64) cnt64[tid]=0;
  __syncthreads();
  for(int e=tid;e<EG_;e+=256){
    int d=ei[E_+e];
    unsigned t=(unsigned)(d-nb);
    if(t<64u) atomicAdd(&cnt64[t],1);
  }
  __syncthreads();
  if(tid<64){
    int v=cnt64[tid], s=v;
    #pragma unroll
    for(int o=1;o<64;o<<=1){ int u=__shfl_up(s,o,64); if(tid>=o) s+=u; }
    int ex=s-v;
    offT[bid*65+tid]=ex;
    cur64[tid]=ex;
    if(tid==63) offT[bid*65+64]=s;
  }
  __syncthreads();
  for(int e=tid;e<EG_;e+=256){
    int s=ei[e];
    int d=ei[E_+e];
    unsigned t=(unsigned)(d-nb);
    if(t<64u){
      int p=atomicAdd(&cur64[t],1);
      if(p<TCAP_) srcs2[bid*TCAP_+p]=s|(d<<16);
    }
  }
}

__device__ __forceinline__ void upadd(float* a, uint4 qa, uint4 qb){
  unsigned int t[8]={qa.x,qa.y,qa.z,qa.w,qb.x,qb.y,qb.z,qb.w};
  #pragma unroll
  for(int j=0;j<8;j++){
    a[2*j]   += __uint_as_float(t[j]<<16);
    a[2*j+1] += __uint_as_float(t[j]&0xffff0000u);
  }
}

// XOR-swizzled LDS agg tile helpers (rows 128B, swizzle bits 4..6 by row&7)
__device__ __forceinline__ void stw16(char* base, int r, int chunk, unsigned int p0,
                                      unsigned int p1, unsigned int p2, unsigned int p3){
  int byte = r*128 + chunk*16;
  byte ^= (r&7)<<4;
  *(uint4*)(base + byte) = (uint4){p0,p1,p2,p3};
}
__device__ __forceinline__ bf8v ld16(const char* base, int r, int chunk){
  int byte = r*128 + chunk*16;
  byte ^= (r&7)<<4;
  return *(const bf8v*)(base + byte);
}

// ---------------- fused layer: shared-topology SpMM (wide rows) -> MFMA -> epilogue ----------------
// h layout: [node][g*64+c] (4096 bf16 = 8KB per node row). Block owns 2 dst nodes.
// Phase A: each edge processed ONCE for all 64 graphs; 256 threads x 32B coalesced
// streaming adds into register accumulators (all source loads independent).
// Phase B: M=128 rows (2 dst x 64 g), K=128 [agg|root], N=64 via MFMA.
__global__ __launch_bounds__(256,4) void k_layer(const unsigned short* __restrict__ hs,
    unsigned short* __restrict__ hd, const int* __restrict__ offT, const int* __restrict__ srcs2,
    const unsigned short* __restrict__ wcat, const float* __restrict__ brel,
    const float* __restrict__ lng, const float* __restrict__ lnb, int do_ln){
  __shared__ uint4 aggl4[1024];      // 16 KB: [128 rows][128 B] swizzled
  char* agglc=(char*)aggl4;
  int tid=threadIdx.x;
  int w=tid>>6, lane=tid&63;
  int dst0=blockIdx.x*2;

  // ---- phase A: gather (shared topology, register accumulation) ----
  {
    int jj=dst0>>6, loc=dst0&63;
    int kb=offT[jj*65+loc];
    int ke=offT[jj*65+loc+2];
    const int* esp=srcs2 + jj*TCAP_;
    int co=tid*16;                   // bf16 channel offset within 4096-wide row
    float aA[16], aB[16];
    #pragma unroll
    for(int c=0;c<16;c++){ aA[c]=0.f; aB[c]=0.f; }
    int k=kb;
    for(; k+1<ke; k+=2){
      int u0=esp[k], u1=esp[k+1];
      const unsigned short* r0=hs+(size_t)(u0&0xffff)*4096+co;
      const unsigned short* r1=hs+(size_t)(u1&0xffff)*4096+co;
      uint4 qa0=*(const uint4*)r0, qb0=*(const uint4*)(r0+8);
      uint4 qa1=*(const uint4*)r1, qb1=*(const uint4*)(r1+8);
      if((u0>>16)==dst0) upadd(aA,qa0,qb0); else upadd(aB,qa0,qb0);
      if((u1>>16)==dst0) upadd(aA,qa1,qb1); else upadd(aB,qa1,qb1);
    }
    if(k<ke){
      int u0=esp[k];
      const unsigned short* r0=hs+(size_t)(u0&0xffff)*4096+co;
      uint4 qa0=*(const uint4*)r0, qb0=*(const uint4*)(r0+8);
      if((u0>>16)==dst0) upadd(aA,qa0,qb0); else upadd(aB,qa0,qb0);
    }
    // pack to bf16, store swizzled LDS
    unsigned int pA[8], pB[8];
    #pragma unroll
    for(int j=0;j<8;j++){
      pA[j]=(unsigned int)f2bf(aA[2*j]) | ((unsigned int)f2bf(aA[2*j+1])<<16);
      pB[j]=(unsigned int)f2bf(aB[2*j]) | ((unsigned int)f2bf(aB[2*j+1])<<16);
    }
    int rl=tid>>2, c2=(tid&3)*2;
    stw16(agglc, rl,    c2,   pA[0],pA[1],pA[2],pA[3]);
    stw16(agglc, rl,    c2+1, pA[4],pA[5],pA[6],pA[7]);
    stw16(agglc, 64+rl, c2,   pB[0],pB[1],pB[2],pB[3]);
    stw16(agglc, 64+rl, c2+1, pB[4],pB[5],pB[6],pB[7]);
  }
  __syncthreads();

  // ---- phase B: MFMA [agg|root] @ Wcat^T, fused epilogue ----
  int m=lane&15, quad=lane>>4;
  f4v acc[2][4];
  float bias_nt[4], g_nt[4], b_nt[4];
  #pragma unroll
  for(int nt=0;nt<4;nt++){
    int c=nt*16+m;
    bias_nt[nt]=brel[c];
    g_nt[nt]=lng[c]; b_nt[nt]=lnb[c];
    acc[0][nt]=(f4v){0.f,0.f,0.f,0.f};
    acc[1][nt]=(f4v){0.f,0.f,0.f,0.f};
  }
  #pragma unroll
  for(int mt=0;mt<2;mt++){
    int R=w*32+mt*16+m;
    bf8v af0=ld16(agglc,R,quad);
    bf8v af1=ld16(agglc,R,4+quad);
    int dn=dst0+(R>>6), gg=R&63;
    const unsigned short* hrow=hs+(size_t)dn*4096+gg*64;
    bf8v af2=*(const bf8v*)(hrow+quad*8);
    bf8v af3=*(const bf8v*)(hrow+32+quad*8);
    #pragma unroll
    for(int nt=0;nt<4;nt++){
      const unsigned short* wrow=wcat + (long)(nt*16+m)*128 + quad*8;
      bf8v b0=*(const bf8v*)(wrow);
      bf8v b1=*(const bf8v*)(wrow+32);
      bf8v b2=*(const bf8v*)(wrow+64);
      bf8v b3=*(const bf8v*)(wrow+96);
      acc[mt][nt]=__builtin_amdgcn_mfma_f32_16x16x32_bf16(af0,b0,acc[mt][nt],0,0,0);
      acc[mt][nt]=__builtin_amdgcn_mfma_f32_16x16x32_bf16(af1,b1,acc[mt][nt],0,0,0);
      acc[mt][nt]=__builtin_amdgcn_mfma_f32_16x16x32_bf16(af2,b2,acc[mt][nt],0,0,0);
      acc[mt][nt]=__builtin_amdgcn_mfma_f32_16x16x32_bf16(af3,b3,acc[mt][nt],0,0,0);
    }
  }
  #pragma unroll
  for(int mt=0;mt<2;mt++){
    float v[4][4];
    #pragma unroll
    for(int nt=0;nt<4;nt++)
      #pragma unroll
      for(int r=0;r<4;r++)
        v[nt][r]=fmaxf(acc[mt][nt][r]+bias_nt[nt],0.f);
    if(do_ln){
      #pragma unroll
      for(int r=0;r<4;r++){
        float rs=v[0][r]+v[1][r]+v[2][r]+v[3][r];
        float rss=v[0][r]*v[0][r]+v[1][r]*v[1][r]+v[2][r]*v[2][r]+v[3][r]*v[3][r];
        #pragma unroll
        for(int o=1;o<16;o<<=1){ rs+=__shfl_xor(rs,o,64); rss+=__shfl_xor(rss,o,64); }
        float mu=rs*(1.f/64.f);
        float var=rss*(1.f/64.f)-mu*mu;
        float inv=rsqrtf(var+EPS_);
        #pragma unroll
        for(int nt=0;nt<4;nt++) v[nt][r]=(v[nt][r]-mu)*inv*g_nt[nt]+b_nt[nt];
      }
    }
    #pragma unroll
    for(int r=0;r<4;r++){
      int R=w*32+mt*16+quad*4+r;
      int dn=dst0+(R>>6), gg=R&63;
      unsigned short* out=hd + (size_t)dn*4096 + gg*64;
      #pragma unroll
      for(int nt=0;nt<4;nt++) out[nt*16+m]=f2bf(v[nt][r]);
    }
  }
}

// ---------------- merged readouts; also emit double-bf16 pf rows for md GEMM ----------------
__global__ __launch_bounds__(256) void k_readout2(const unsigned short* __restrict__ h,
    const int* __restrict__ prodi, const int* __restrict__ linei,
    const float* __restrict__ pw, const float* __restrict__ pb,
    const float* __restrict__ fw, const float* __restrict__ fb,
    float* __restrict__ outp, float* __restrict__ outf,
    unsigned short* __restrict__ pfhi, unsigned short* __restrict__ pflo){
  int i=blockIdx.x*256+threadIdx.x;
  const int MP=B_*G_;
  const int MT=MP+B_*F_;
  if(i>=MT) return;
  bool isp=i<MP;
  int j=isp? i : i-MP;
  unsigned nf=(unsigned)(isp? prodi[j] : linei[j]);
  unsigned gg=nf/(unsigned)N_;
  unsigned node=nf-gg*(unsigned)N_;
  const float* wv=isp? pw:fw;
  float acc=isp? pb[0]:fb[0];
  const uint4* hp=(const uint4*)(h + (size_t)node*4096 + gg*64);
  #pragma unroll
  for(int c=0;c<8;c++){
    uint4 u=hp[c];
    unsigned int uu[4]={u.x,u.y,u.z,u.w};
    #pragma unroll
    for(int q=0;q<4;q++){
      float lo=__uint_as_float(uu[q]<<16);
      float hi=__uint_as_float(uu[q]&0xffff0000u);
      acc += lo*wv[c*8+2*q] + hi*wv[c*8+2*q+1];
    }
  }
  int b,kcol;
  if(isp){ outp[j]=acc; b=j/G_; kcol=j%G_; }
  else   { outf[j]=acc; b=j/F_; kcol=G_+j%F_; }
  unsigned short hi=f2bf(acc);
  pfhi[(long)b*KTOT_+kcol]=hi;
  pflo[(long)b*KTOT_+kcol]=f2bf(acc-bf2f(hi));
}

// ---------------- md dense GEMM: outmd[b][l] -= sum_k mask[l][k]*pf[b][k] ----------------
// outmd pre-initialized with demand by k_prep; atomics accumulate -acc directly.
__global__ __launch_bounds__(256) void k_md_gemm(const float* __restrict__ gm, const float* __restrict__ lm,
    const unsigned short* __restrict__ pfhi, const unsigned short* __restrict__ pflo,
    float* __restrict__ outmd){
  int tid=threadIdx.x;
  int w=tid>>6, lane=tid&63;
  int m=lane&15, quad=lane>>4;
  int lb=blockIdx.x>>3, kc=blockIdx.x&7;
  int l=lb*64 + w*16 + m;              // A (mask) row for this lane
  f4v acc[4];
  #pragma unroll
  for(int nt=0;nt<4;nt++) acc[nt]=(f4v){0.f,0.f,0.f,0.f};
  int kk0=kc*KCH_;
  for(int s=0;s<KCH_/32;s++){
    int kk=kk0+s*32;
    const float* ap = (kk<G_)? gm + (long)l*G_ + kk : lm + (long)l*F_ + (kk-G_);
    float4 a0=*(const float4*)(ap+quad*8);
    float4 a1=*(const float4*)(ap+quad*8+4);
    bf8v af;
    af[0]=(short)f2bf(a0.x); af[1]=(short)f2bf(a0.y);
    af[2]=(short)f2bf(a0.z); af[3]=(short)f2bf(a0.w);
    af[4]=(short)f2bf(a1.x); af[5]=(short)f2bf(a1.y);
    af[6]=(short)f2bf(a1.z); af[7]=(short)f2bf(a1.w);
    #pragma unroll
    for(int nt=0;nt<4;nt++){
      int b=nt*16+m;
      const unsigned short* bp=pfhi + (long)b*KTOT_ + kk + quad*8;
      const unsigned short* lp=pflo + (long)b*KTOT_ + kk + quad*8;
      bf8v bh=*(const bf8v*)bp;
      bf8v bl=*(const bf8v*)lp;
      acc[nt]=__builtin_amdgcn_mfma_f32_16x16x32_bf16(af,bh,acc[nt],0,0,0);
      acc[nt]=__builtin_amdgcn_mfma_f32_16x16x32_bf16(af,bl,acc[nt],0,0,0);
    }
  }
  int lrow=lb*64 + w*16 + quad*4;
  #pragma unroll
  for(int r=0;r<4;r++)
    #pragma unroll
    for(int nt=0;nt<4;nt++)
      atomicAdd(&outmd[(long)(nt*16+m)*L_ + lrow+r], -acc[nt][r]);
}

extern "C" void kernel_launch(void* const* d_in, const int* in_sizes, int n_in,
                              void* d_out, int out_size, void* d_ws, size_t ws_size,
                              hipStream_t stream){
  const float* x    =(const float*)d_in[0];
  const int*   ei   =(const int*)d_in[1];
  const int*   prodi=(const int*)d_in[2];
  const int*   linei=(const int*)d_in[3];
  const int*   loci =(const int*)d_in[4];
  const float* ew   =(const float*)d_in[5];
  const float* eb   =(const float*)d_in[6];
  const float* lng  =(const float*)d_in[7];
  const float* lnb  =(const float*)d_in[8];
  const float* wrel =(const float*)d_in[9];
  const float* brel =(const float*)d_in[10];
  const float* wroot=(const float*)d_in[11];
  const float* pw   =(const float*)d_in[12];
  const float* pb   =(const float*)d_in[13];
  const float* fw   =(const float*)d_in[14];
  const float* fb   =(const float*)d_in[15];
  const float* gm   =(const float*)d_in[16];
  const float* lm   =(const float*)d_in[17];

  char* ws=(char*)d_ws;
  unsigned short* hnA =(unsigned short*)ws;                        // NT*64 bf16 ([n][g*64+c])
  unsigned short* hnB =hnA + (size_t)NT_*64;                       // NT*64 bf16
  unsigned short* wcat=hnB + (size_t)NT_*64;                       // 32768 bf16
  unsigned short* pfhi=wcat + 32768;                               // B*KTOT bf16
  unsigned short* pflo=pfhi + (size_t)B_*KTOT_;                    // B*KTOT bf16
  int* offT =(int*)(pflo + (size_t)B_*KTOT_);                      // 88*65 int
  int* srcs2=offT + 88*65;                                         // 88*TCAP int

  float* outp =(float*)d_out;
  float* outf =outp + (size_t)B_*G_;
  float* outmd=outf + (size_t)B_*F_;

  k_prep<<<600+NT_/32,256,0,stream>>>(ei,wcat,wrel,wroot,offT,srcs2,
                                      x,loci,outmd,hnA,ew,eb,lng,lnb);
  for(int i=0;i<4;i++){
    const unsigned short* hs=(i&1)?hnB:hnA;
    unsigned short* hd=(i&1)?hnA:hnB;
    k_layer<<<N_/2,256,0,stream>>>(hs,hd,offT,srcs2,wcat+(size_t)i*8192,
        brel+(size_t)i*64,lng,lnb,(i<3)?1:0);
  }
  // after 4 layers (A->B->A->B->A) result is in hnA
  {
    int MT=B_*(G_+F_);
    k_readout2<<<(MT+255)/256,256,0,stream>>>(hnA,prodi,linei,pw,pb,fw,fb,outp,outf,pfhi,pflo);
  }
  k_md_gemm<<<256,256,0,stream>>>(gm,lm,pfhi,pflo,outmd);
}